// Round 8
// baseline (896.947 us; speedup 1.0000x reference)
//
#include <hip/hip_runtime.h>
#include <hip/hip_bf16.h>
#include <hip/hip_cooperative_groups.h>

namespace cg = cooperative_groups;

#define HH 96
#define WW 96
#define CC 21
#define NN (HH*WW)          // 9216
#define NELEM (NN*CC)       // 193536
#define RS 20               // blur radius: exp(-400/18)=2e-10 tail, negligible
#define NPAR (2*CC + CC*CC)
#define L2E 1.4426950408889634f
#define MCHUNK 384
#define SKM 24              // 24*384 = 9216 m-splits
#define MSTEPS (MCHUNK/16)  // 24
#define NBB (36*SKM)        // 864 bilateral jobs
#define NSTRIP 8
#define NBLUR (CC*NSTRIP)   // 168 blur jobs
#define NJOBS (NBB + NBLUR) // 1032
#define SROWS 12
#define SMEM_BYTES 14848    // max(bilateral 12288, blur 14676, update 1932)

typedef short bf16x8 __attribute__((ext_vector_type(8)));
typedef float f32x16 __attribute__((ext_vector_type(16)));

__device__ __forceinline__ float fexp2(float x) { return __builtin_amdgcn_exp2f(x); }
__device__ __forceinline__ float fexp(float x)  { return __builtin_amdgcn_exp2f(x * L2E); }

__device__ __forceinline__ short f2b(float f) {
    __hip_bfloat16 h = __float2bfloat16(f);
    short s; __builtin_memcpy(&s, &h, 2); return s;
}
__device__ __forceinline__ float b2f(unsigned short v) {
    union { unsigned u; float f; } x; x.u = ((unsigned)v) << 16; return x.f;
}

// ======================= device work functions =======================

// prep chunk: convert u->uf, softmax->pT(bf16 c-major), featx, params, zero bil
__device__ __forceinline__ void dev_prep(
    int chunk, int tid, int f,
    const void* u, const void* img, const void* wS, const void* wB,
    const void* compat, float* uf, float* featx, float* par,
    float* bil, __hip_bfloat16* pT)
{
    const int n = chunk * 256 + tid;
    if (chunk == 0) {
        for (int i = tid; i < NPAR; i += 256) {
            const void* src; int j;
            if (i < CC)        { src = wS;     j = i; }
            else if (i < 2*CC) { src = wB;     j = i - CC; }
            else               { src = compat; j = i - 2*CC; }
            par[i] = f ? ((const float*)src)[j]
                       : __bfloat162float(((const __hip_bfloat16*)src)[j]);
        }
    }
    {   // featx[n]: log2-prescaled symmetric bilateral features
        float c0, c1, c2;
        if (f) { const float* p = (const float*)img;
                 c0 = p[3*n]; c1 = p[3*n+1]; c2 = p[3*n+2]; }
        else   { const __hip_bfloat16* p = (const __hip_bfloat16*)img;
                 c0 = __bfloat162float(p[3*n]); c1 = __bfloat162float(p[3*n+1]);
                 c2 = __bfloat162float(p[3*n+2]); }
        float ym = (float)(n / WW), xm = (float)(n % WW);
        const float sc = 0.15014029f;   // sqrt(2*L2E/128)
        const float cf = 9.6089787f;    // sqrt(64*L2E)
        featx[8*n + 0] = -L2E * (fmaf(ym, ym, xm*xm) * 0.0078125f
                                 + 32.f * (c0*c0 + c1*c1 + c2*c2));
        featx[8*n + 1] = sc * ym;
        featx[8*n + 2] = sc * xm;
        featx[8*n + 3] = cf * c0;
        featx[8*n + 4] = cf * c1;
        featx[8*n + 5] = cf * c2;
        featx[8*n + 6] = 0.f;
        featx[8*n + 7] = 0.f;
    }
    float v[CC];
    float mx = -1e30f;
    #pragma unroll
    for (int c = 0; c < CC; c++) {
        float uv = f ? ((const float*)u)[n*CC + c]
                     : __bfloat162float(((const __hip_bfloat16*)u)[n*CC + c]);
        uf[n*CC + c] = uv;
        v[c] = uv;
        mx = fmaxf(mx, uv);
    }
    float s = 0.f;
    #pragma unroll
    for (int c = 0; c < CC; c++) { v[c] = fexp(v[c] - mx); s += v[c]; }
    float inv = 1.f / s;
    #pragma unroll
    for (int c = 0; c < CC; c++) {
        pT[(size_t)c*NN + n] = __float2bfloat16(v[c] * inv);
        bil[(size_t)c*NN + n] = 0.f;
    }
}

// MFMA bilateral job: bil[c][n] += sum_{m in chunk} pT[c][m] * K(n,m)
// D(32c x 32n) = A(32c x 16m) * B(16m x 32n), v_mfma_f32_32x32x16_bf16.
// pT rows 21..31 garbage -> pollute only D rows 21..31 (never stored).
__device__ __forceinline__ void dev_bilateral(
    int job, int tid, const __hip_bfloat16* pT, const float* featx,
    float* bil, float* lds_h)
{
    const int nblk = job % 36, mblk = job / 36;
    const int wv   = tid >> 6, lane = tid & 63;
    const int quad = lane >> 5, lid = lane & 31;
    const int m0c  = mblk * MCHUNK;

    __syncthreads();   // previous smem users done
    {   // stage featx chunk (coalesced float4 copy)
        const float4* src = (const float4*)(featx + (size_t)m0c * 8);
        float4* dst = (float4*)lds_h;
        for (int i = tid; i < MCHUNK * 2; i += 256) dst[i] = src[i];
    }
    __syncthreads();

    const int n0 = nblk * 256 + wv * 64 + lid;    // tile0; tile1 = n0+32
    const float4 g0a = *(const float4*)(featx + (size_t)n0 * 8);
    const float4 g0b = *(const float4*)(featx + (size_t)n0 * 8 + 4);
    const float4 g1a = *(const float4*)(featx + (size_t)(n0 + 32) * 8);
    const float4 g1b = *(const float4*)(featx + (size_t)(n0 + 32) * 8 + 4);

    f32x16 acc0, acc1;
    #pragma unroll
    for (int r = 0; r < 16; r++) { acc0[r] = 0.f; acc1[r] = 0.f; }

    #pragma unroll 1
    for (int step = 0; step < MSTEPS; step++) {
        const int m0 = m0c + step * 16;
        bf16x8 afrag = *(const bf16x8*)(pT + (size_t)lid * NN + m0 + quad * 8);

        const float* h = lds_h + (step * 16 + quad * 8) * 8;
        float kb0[8], kb1[8];
        #pragma unroll
        for (int j = 0; j < 8; j++) {
            float4 ha = *(const float4*)(h + j * 8);
            float4 hb = *(const float4*)(h + j * 8 + 4);
            float s0 = g0a.x + ha.x;
            s0 = fmaf(g0a.y, ha.y, s0);
            s0 = fmaf(g0a.z, ha.z, s0);
            s0 = fmaf(g0a.w, ha.w, s0);
            s0 = fmaf(g0b.x, hb.x, s0);
            s0 = fmaf(g0b.y, hb.y, s0);
            kb0[j] = fexp2(s0);
            float s1 = g1a.x + ha.x;
            s1 = fmaf(g1a.y, ha.y, s1);
            s1 = fmaf(g1a.z, ha.z, s1);
            s1 = fmaf(g1a.w, ha.w, s1);
            s1 = fmaf(g1b.x, hb.x, s1);
            s1 = fmaf(g1b.y, hb.y, s1);
            kb1[j] = fexp2(s1);
        }
        bf16x8 b0, b1;
        #pragma unroll
        for (int j = 0; j < 8; j++) { b0[j] = f2b(kb0[j]); b1[j] = f2b(kb1[j]); }

        acc0 = __builtin_amdgcn_mfma_f32_32x32x16_bf16(afrag, b0, acc0, 0, 0, 0);
        acc1 = __builtin_amdgcn_mfma_f32_32x32x16_bf16(afrag, b1, acc1, 0, 0, 0);
    }

    // D layout: col(n) = lid, row(c) = (r&3) + 8*(r>>2) + 4*quad
    #pragma unroll
    for (int r = 0; r < 16; r++) {
        int c = (r & 3) + 8 * (r >> 2) + 4 * quad;
        if (c < CC) {
            atomicAdd(&bil[(size_t)c * NN + n0],      acc0[r]);
            atomicAdd(&bil[(size_t)c * NN + n0 + 32], acc1[r]);
        }
    }
}

// Spatial blur job: one (channel, 12-row strip). Halo strip kept as raw bf16.
__device__ __forceinline__ void dev_blur(
    int job, int tid, const __hip_bfloat16* pT, float* s2T,
    unsigned short* A, float* B2, float* w_s)
{
    __syncthreads();   // previous smem users done
    const int c = job % CC;
    const int strip = job / CC;
    const int y0 = strip * SROWS;
    const int ylo = (y0 - RS < 0) ? 0 : y0 - RS;
    const int yhi = (y0 + SROWS - 1 + RS > HH - 1) ? HH - 1 : y0 + SROWS - 1 + RS;
    const int nrows = yhi - ylo + 1;

    if (tid <= RS) w_s[tid] = fexp2(-(float)(tid*tid) * (L2E / 18.f));
    const unsigned short* src = (const unsigned short*)(pT + (size_t)c * NN + ylo * WW);
    for (int i = tid; i < nrows * WW; i += 256) A[i] = src[i];
    __syncthreads();

    for (int i = tid; i < SROWS * WW; i += 256) {
        const int yo = y0 + i / WW;
        const int x  = i % WW;
        float acc = b2f(A[(yo - ylo) * WW + x]);
        #pragma unroll
        for (int d = 1; d <= RS; d++) {
            float s = 0.f;
            if (yo - d >= 0)  s += b2f(A[(yo - d - ylo) * WW + x]);
            if (yo + d < HH)  s += b2f(A[(yo + d - ylo) * WW + x]);
            acc = fmaf(w_s[d], s, acc);
        }
        B2[i] = acc;
    }
    __syncthreads();

    for (int i = tid; i < SROWS * WW; i += 256) {
        const int r = i / WW, x = i % WW;
        float acc = B2[i];
        #pragma unroll
        for (int d = 1; d <= RS; d++) {
            float s = 0.f;
            if (x - d >= 0)  s += B2[r * WW + x - d];
            if (x + d < WW)  s += B2[r * WW + x + d];
            acc = fmaf(w_s[d], s, acc);
        }
        s2T[(size_t)c * NN + (y0 + r) * WW + x] = acc;
    }
}

// Update chunk: combine spatial+bilateral, compat, q-update, softmax -> pT
// (or final output). Re-zeroes bil.
__device__ __forceinline__ void dev_update(
    int chunk, int tid, int f, int last,
    float* bil, const float* s2T, const float* uf, const float* par,
    __hip_bfloat16* pT, void* out, float* sc, float* sws, float* swb)
{
    __syncthreads();   // previous smem users done
    for (int i = tid; i < NPAR; i += 256) {
        if (i < CC)        sws[i] = par[i];
        else if (i < 2*CC) swb[i - CC] = par[i];
        else               sc[i - 2*CC] = par[i];
    }
    __syncthreads();

    const int n = chunk * 256 + tid;
    float msg[CC];
    #pragma unroll
    for (int c = 0; c < CC; c++) {
        msg[c] = fmaf(s2T[(size_t)c*NN + n], sws[c], bil[(size_t)c*NN + n] * swb[c]);
        bil[(size_t)c*NN + n] = 0.f;
    }

    float qv[CC];
    float mx = -1e30f;
    #pragma unroll
    for (int c = 0; c < CC; c++) {
        float pw = 0.f;
        #pragma unroll
        for (int cp = 0; cp < CC; cp++) pw = fmaf(msg[cp], sc[c*CC + cp], pw);
        qv[c] = uf[n*CC + c] - pw;
        mx = fmaxf(mx, qv[c]);
    }

    if (last) {
        #pragma unroll
        for (int c = 0; c < CC; c++) {
            if (f) ((float*)out)[n*CC + c] = qv[c];
            else ((__hip_bfloat16*)out)[n*CC + c] = __float2bfloat16(qv[c]);
        }
    } else {
        float s = 0.f;
        #pragma unroll
        for (int c = 0; c < CC; c++) { qv[c] = fexp(qv[c] - mx); s += qv[c]; }
        float inv = 1.f / s;
        #pragma unroll
        for (int c = 0; c < CC; c++)
            pT[(size_t)c*NN + n] = __float2bfloat16(qv[c] * inv);
    }
}

// ======================= fused cooperative kernel =======================
__global__ __launch_bounds__(256, 4) void k_fused(
    const void* __restrict__ u, const void* __restrict__ img,
    const void* __restrict__ wS, const void* __restrict__ wB,
    const void* __restrict__ compat, int* __restrict__ slots,
    float* __restrict__ uf, float* __restrict__ featx, float* __restrict__ par,
    float* __restrict__ bil, float* __restrict__ s2T,
    __hip_bfloat16* __restrict__ pT, void* __restrict__ out)
{
    cg::grid_group grid = cg::this_grid();
    __shared__ __align__(16) char smem[SMEM_BYTES];
    const int tid = threadIdx.x;
    const int bid = blockIdx.x;
    const int G   = gridDim.x;

    // phase 0: dtype sniff (grid-stride over 36 pixel-chunks)
    for (int chunk = bid; chunk < 36; chunk += G) {
        const unsigned short* u16 = (const unsigned short*)u;
        const int gt = chunk * 256 + tid;    // x21 covers NELEM exactly
        int found = 0;
        #pragma unroll
        for (int k = 0; k < 21; k++)
            if ((u16[gt * 21 + k] & 0x7F80u) == 0x7F80u) found = 1;
        int* si = (int*)smem;
        si[tid] = found;
        __syncthreads();
        if (tid == 0) {
            int any = 0;
            for (int i = 0; i < 256; i++) any |= si[i];
            slots[chunk] = any;              // 1 = fp32 inputs, 0 = bf16
        }
        __syncthreads();
    }
    grid.sync();

    // all blocks derive the dtype flag
    int f = 0;
    #pragma unroll 1
    for (int i = 0; i < 36; i++) f |= slots[i];

    // phase 1: prep
    for (int chunk = bid; chunk < 36; chunk += G)
        dev_prep(chunk, tid, f, u, img, wS, wB, compat, uf, featx, par, bil, pT);
    grid.sync();

    // 5 mean-field iterations
    #pragma unroll 1
    for (int it = 0; it < 5; it++) {
        #pragma unroll 1
        for (int job = bid; job < NJOBS; job += G) {
            if (job < NBB)
                dev_bilateral(job, tid, pT, featx, bil, (float*)smem);
            else
                dev_blur(job - NBB, tid, pT, s2T,
                         (unsigned short*)smem, (float*)(smem + 9984),
                         (float*)(smem + 14592));
        }
        grid.sync();
        for (int chunk = bid; chunk < 36; chunk += G)
            dev_update(chunk, tid, f, it == 4, bil, s2T, uf, par, pT, out,
                       (float*)smem, (float*)smem + 441, (float*)smem + 462);
        if (it < 4) grid.sync();
    }
}

// ======================= fallback (non-cooperative) =======================
__global__ void k_sniff_fb(const unsigned short* __restrict__ u16,
                           int* __restrict__ flag) {
    __shared__ int sfound;
    if (threadIdx.x == 0) sfound = 0;
    __syncthreads();
    int found = 0;
    for (int i = threadIdx.x; i < NELEM; i += 1024)
        if ((u16[i] & 0x7F80u) == 0x7F80u) found = 1;
    if (found) sfound = 1;
    __syncthreads();
    if (threadIdx.x == 0) *flag = sfound;
}

__global__ __launch_bounds__(256) void k_prep_fb(
    const void* u, const void* img, const void* wS, const void* wB,
    const void* compat, const int* __restrict__ flag,
    float* uf, float* featx, float* par, float* bil, __hip_bfloat16* pT) {
    dev_prep(blockIdx.x, threadIdx.x, *flag, u, img, wS, wB, compat,
             uf, featx, par, bil, pT);
}

__global__ __launch_bounds__(256) void k_work_fb(
    const __hip_bfloat16* __restrict__ pT, const float* __restrict__ featx,
    float* __restrict__ bil, float* __restrict__ s2T) {
    __shared__ __align__(16) char smem[SMEM_BYTES];
    const int bid = blockIdx.x;
    if (bid < NBB)
        dev_bilateral(bid, threadIdx.x, pT, featx, bil, (float*)smem);
    else
        dev_blur(bid - NBB, threadIdx.x, pT, s2T,
                 (unsigned short*)smem, (float*)(smem + 9984),
                 (float*)(smem + 14592));
}

__global__ __launch_bounds__(256) void k_update_fb(
    float* bil, const float* s2T, const float* uf, const float* par,
    const int* __restrict__ flag, __hip_bfloat16* pT, void* out, int last) {
    __shared__ __align__(16) char smem[SMEM_BYTES];
    dev_update(blockIdx.x, threadIdx.x, *flag, last, bil, s2T, uf, par, pT, out,
               (float*)smem, (float*)smem + 441, (float*)smem + 462);
}

// ======================= host launcher =======================
extern "C" void kernel_launch(void* const* d_in, const int* in_sizes, int n_in,
                              void* d_out, int out_size, void* d_ws, size_t ws_size,
                              hipStream_t stream)
{
    float* ws = (float*)d_ws;
    int*   slots = (int*)ws;                     // [0..64): sniff slots; [40]: fb flag
    float* par   = ws + 64;                      // [64..576)
    float* featx = ws + 576;                     // NN*8
    __hip_bfloat16* pT = (__hip_bfloat16*)(ws + 576 + NN*8);  // 32*NN bf16
    float* uf  = ws + 576 + NN*8 + 16*NN;        // NELEM
    float* s2T = uf + NELEM;                     // NELEM (c-major)
    float* bil = s2T + NELEM;                    // NELEM (c-major)

    const void* A_u   = d_in[0];
    const void* A_img = d_in[1];
    const void* A_wS  = d_in[2];
    const void* A_wB  = d_in[3];
    const void* A_cm  = d_in[4];
    void* A_out = d_out;
    void* args[] = {(void*)&A_u, (void*)&A_img, (void*)&A_wS, (void*)&A_wB,
                    (void*)&A_cm, (void*)&slots, (void*)&uf, (void*)&featx,
                    (void*)&par, (void*)&bil, (void*)&s2T, (void*)&pT,
                    (void*)&A_out};

    // size the cooperative grid by occupancy (deterministic device query)
    int nb = 0;
    hipError_t oe = hipOccupancyMaxActiveBlocksPerMultiprocessor(&nb, k_fused, 256, 0);
    hipError_t le = hipErrorUnknown;
    if (oe == hipSuccess && nb > 0) {
        int G = nb * 256;                        // 256 CUs on MI355X
        if (G > NJOBS) G = NJOBS;
        le = hipLaunchCooperativeKernel((void*)k_fused, dim3(G), dim3(256),
                                        args, 0, stream);
    }
    if (le != hipSuccess) {
        // fallback: equivalent multi-dispatch pipeline (same device functions)
        int* flag = slots + 40;
        k_sniff_fb<<<1, 1024, 0, stream>>>((const unsigned short*)d_in[0], flag);
        k_prep_fb<<<36, 256, 0, stream>>>(A_u, A_img, A_wS, A_wB, A_cm, flag,
                                          uf, featx, par, bil, pT);
        for (int it = 0; it < 5; it++) {
            k_work_fb<<<NJOBS, 256, 0, stream>>>(pT, featx, bil, s2T);
            k_update_fb<<<36, 256, 0, stream>>>(bil, s2T, uf, par, flag,
                                                pT, d_out, (it == 4) ? 1 : 0);
        }
    }
}

// Round 9
// 508.412 us; speedup vs baseline: 1.7642x; 1.7642x over previous
//
#include <hip/hip_runtime.h>
#include <hip/hip_bf16.h>

#define HH 96
#define WW 96
#define CC 21
#define NN (HH*WW)          // 9216
#define NELEM (NN*CC)       // 193536
#define RS 20               // blur radius: exp(-400/18)=2e-10 tail, negligible
#define NPAR (2*CC + CC*CC) // 483
#define L2E 1.4426950408889634f
#define MCHUNK 384
#define SKM 24              // 24*384 = 9216 m-splits
#define MSTEPS (MCHUNK/16)  // 24
#define NBB (36*SKM)        // 864 bilateral jobs
#define SROWS 8             // 8 rows per blur strip -> exactly 3 n-chunks
#define NSTRIP (HH/SROWS)   // 12
#define NBLUR (CC*NSTRIP)   // 252 blur jobs
#define NJOBS (NBB + NBLUR) // 1116
#define NCHUNK 36           // n-chunks of 256 pixels
#define CTARGET (SKM + CC)  // 45 producers per chunk
#define SMEM_BYTES 12416

typedef short bf16x8 __attribute__((ext_vector_type(8)));
typedef float f32x16 __attribute__((ext_vector_type(16)));

__device__ __forceinline__ float fexp2(float x) { return __builtin_amdgcn_exp2f(x); }
__device__ __forceinline__ float fexp(float x)  { return __builtin_amdgcn_exp2f(x * L2E); }

// pack two f32 -> two bf16 (truncation) in one v_perm_b32
__device__ __forceinline__ unsigned pk_bf16(float lo, float hi) {
    unsigned a = __builtin_bit_cast(unsigned, hi);
    unsigned b = __builtin_bit_cast(unsigned, lo);
    return __builtin_amdgcn_perm(a, b, 0x07060302u);
}

// ======================= prep (36 blocks x 256) =======================
// Every block independently sniffs dtype from ALL of u (bf16 data never has
// exp=0xFF bit patterns; fp32-as-u16 hits them ~0.4%/word), then converts its
// 256 pixels: uf, softmax->pTA (bf16 c-major), featx, params, zero bil+cnt.
__global__ __launch_bounds__(256) void k_prep(
    const void* __restrict__ u, const void* __restrict__ img,
    const void* __restrict__ wS, const void* __restrict__ wB,
    const void* __restrict__ compat,
    float* __restrict__ uf, float* __restrict__ featx, float* __restrict__ par,
    float* __restrict__ bil, __hip_bfloat16* __restrict__ pT,
    int* __restrict__ cnt, int* __restrict__ flag)
{
    __shared__ int sred[256];
    const int tid = threadIdx.x;
    const int n = blockIdx.x * 256 + tid;

    // ---- dtype sniff over whole u (193536 u16 = 24192 uint4)
    int found = 0;
    const uint4* u4 = (const uint4*)u;
    for (int i = tid; i < NELEM/8; i += 256) {
        uint4 v = u4[i];
        unsigned w;
        w = v.x; found |= ((w & 0x7F800000u) == 0x7F800000u) | ((w & 0x7F80u) == 0x7F80u);
        w = v.y; found |= ((w & 0x7F800000u) == 0x7F800000u) | ((w & 0x7F80u) == 0x7F80u);
        w = v.z; found |= ((w & 0x7F800000u) == 0x7F800000u) | ((w & 0x7F80u) == 0x7F80u);
        w = v.w; found |= ((w & 0x7F800000u) == 0x7F800000u) | ((w & 0x7F80u) == 0x7F80u);
    }
    sred[tid] = found;
    __syncthreads();
    for (int s = 128; s > 0; s >>= 1) {
        if (tid < s) sred[tid] |= sred[tid + s];
        __syncthreads();
    }
    const int f = sred[0];            // 1 = fp32 inputs, 0 = bf16

    if (blockIdx.x == 0) {
        if (tid == 0) *flag = f;
        if (tid < NCHUNK) cnt[tid] = 0;
        for (int i = tid; i < NPAR; i += 256) {
            const void* src; int j;
            if (i < CC)        { src = wS;     j = i; }
            else if (i < 2*CC) { src = wB;     j = i - CC; }
            else               { src = compat; j = i - 2*CC; }
            par[i] = f ? ((const float*)src)[j]
                       : __bfloat162float(((const __hip_bfloat16*)src)[j]);
        }
    }

    {   // featx[n]: log2-prescaled symmetric bilateral features
        float c0, c1, c2;
        if (f) { const float* p = (const float*)img;
                 c0 = p[3*n]; c1 = p[3*n+1]; c2 = p[3*n+2]; }
        else   { const __hip_bfloat16* p = (const __hip_bfloat16*)img;
                 c0 = __bfloat162float(p[3*n]); c1 = __bfloat162float(p[3*n+1]);
                 c2 = __bfloat162float(p[3*n+2]); }
        float ym = (float)(n / WW), xm = (float)(n % WW);
        const float sc = 0.15014029f;   // sqrt(2*L2E/128)
        const float cf = 9.6089787f;    // sqrt(64*L2E)
        featx[8*n + 0] = -L2E * (fmaf(ym, ym, xm*xm) * 0.0078125f
                                 + 32.f * (c0*c0 + c1*c1 + c2*c2));
        featx[8*n + 1] = sc * ym;
        featx[8*n + 2] = sc * xm;
        featx[8*n + 3] = cf * c0;
        featx[8*n + 4] = cf * c1;
        featx[8*n + 5] = cf * c2;
        featx[8*n + 6] = 0.f;
        featx[8*n + 7] = 0.f;
    }

    float v[CC];
    float mx = -1e30f;
    #pragma unroll
    for (int c = 0; c < CC; c++) {
        float uv = f ? ((const float*)u)[n*CC + c]
                     : __bfloat162float(((const __hip_bfloat16*)u)[n*CC + c]);
        uf[n*CC + c] = uv;
        v[c] = uv;
        mx = fmaxf(mx, uv);
    }
    float s = 0.f;
    #pragma unroll
    for (int c = 0; c < CC; c++) { v[c] = fexp(v[c] - mx); s += v[c]; }
    float inv = 1.f / s;
    #pragma unroll
    for (int c = 0; c < CC; c++) {
        pT[(size_t)c*NN + n] = __float2bfloat16(v[c] * inv);
        bil[(size_t)c*NN + n] = 0.f;
    }
}

// ======================= device work functions =======================

// MFMA bilateral job: bil[c][n] += sum_{m in chunk} pT[c][m] * K(n,m)
// D(32c x 32n) = A(32c x 16m) * B(16m x 32n), v_mfma_f32_32x32x16_bf16.
// pT rows 21..31 garbage -> pollute only D rows 21..31 (never stored).
__device__ __forceinline__ void dev_bilateral(
    int job, int tid, const __hip_bfloat16* pT, const float* featx,
    float* bil, float* lds_h)
{
    const int nblk = job % 36, mblk = job / 36;
    const int wv   = tid >> 6, lane = tid & 63;
    const int quad = lane >> 5, lid = lane & 31;
    const int m0c  = mblk * MCHUNK;

    {   // stage featx chunk (coalesced float4 copy)
        const float4* src = (const float4*)(featx + (size_t)m0c * 8);
        float4* dst = (float4*)lds_h;
        for (int i = tid; i < MCHUNK * 2; i += 256) dst[i] = src[i];
    }
    __syncthreads();

    const int n0 = nblk * 256 + wv * 64 + lid;    // tile0; tile1 = n0+32
    const float4 g0a = *(const float4*)(featx + (size_t)n0 * 8);
    const float4 g0b = *(const float4*)(featx + (size_t)n0 * 8 + 4);
    const float4 g1a = *(const float4*)(featx + (size_t)(n0 + 32) * 8);
    const float4 g1b = *(const float4*)(featx + (size_t)(n0 + 32) * 8 + 4);

    f32x16 acc0, acc1;
    #pragma unroll
    for (int r = 0; r < 16; r++) { acc0[r] = 0.f; acc1[r] = 0.f; }

    #pragma unroll 1
    for (int step = 0; step < MSTEPS; step++) {
        const int m0 = m0c + step * 16;
        bf16x8 afrag = *(const bf16x8*)(pT + (size_t)lid * NN + m0 + quad * 8);

        const float* h = lds_h + (step * 16 + quad * 8) * 8;
        float kb0[8], kb1[8];
        #pragma unroll
        for (int j = 0; j < 8; j++) {
            float4 ha = *(const float4*)(h + j * 8);
            float4 hb = *(const float4*)(h + j * 8 + 4);
            float s0 = g0a.x + ha.x;
            s0 = fmaf(g0a.y, ha.y, s0);
            s0 = fmaf(g0a.z, ha.z, s0);
            s0 = fmaf(g0a.w, ha.w, s0);
            s0 = fmaf(g0b.x, hb.x, s0);
            s0 = fmaf(g0b.y, hb.y, s0);
            kb0[j] = fexp2(s0);
            float s1 = g1a.x + ha.x;
            s1 = fmaf(g1a.y, ha.y, s1);
            s1 = fmaf(g1a.z, ha.z, s1);
            s1 = fmaf(g1a.w, ha.w, s1);
            s1 = fmaf(g1b.x, hb.x, s1);
            s1 = fmaf(g1b.y, hb.y, s1);
            kb1[j] = fexp2(s1);
        }
        union { bf16x8 v; unsigned d[4]; } b0u, b1u;
        #pragma unroll
        for (int d = 0; d < 4; d++) {
            b0u.d[d] = pk_bf16(kb0[2*d], kb0[2*d+1]);
            b1u.d[d] = pk_bf16(kb1[2*d], kb1[2*d+1]);
        }

        acc0 = __builtin_amdgcn_mfma_f32_32x32x16_bf16(afrag, b0u.v, acc0, 0, 0, 0);
        acc1 = __builtin_amdgcn_mfma_f32_32x32x16_bf16(afrag, b1u.v, acc1, 0, 0, 0);
    }

    // D layout: col(n) = lid, row(c) = (r&3) + 8*(r>>2) + 4*quad
    #pragma unroll
    for (int r = 0; r < 16; r++) {
        int c = (r & 3) + 8 * (r >> 2) + 4 * quad;
        if (c < CC) {
            atomicAdd(&bil[(size_t)c * NN + n0],      acc0[r]);
            atomicAdd(&bil[(size_t)c * NN + n0 + 32], acc1[r]);
        }
    }
}

// Spatial blur job: one (channel, 8-row strip). Halo kept as raw bf16.
__device__ __forceinline__ void dev_blur(
    int job, int tid, const __hip_bfloat16* pT, float* s2T,
    unsigned short* A, float* B2, float* w_s)
{
    const int c = job % CC;
    const int strip = job / CC;
    const int y0 = strip * SROWS;
    const int ylo = (y0 - RS < 0) ? 0 : y0 - RS;
    const int yhi = (y0 + SROWS - 1 + RS > HH - 1) ? HH - 1 : y0 + SROWS - 1 + RS;
    const int nrows = yhi - ylo + 1;

    if (tid <= RS) w_s[tid] = fexp2(-(float)(tid*tid) * (L2E / 18.f));
    const unsigned short* src = (const unsigned short*)(pT + (size_t)c * NN + ylo * WW);
    for (int i = tid; i < nrows * WW; i += 256) A[i] = src[i];
    __syncthreads();

    for (int i = tid; i < SROWS * WW; i += 256) {
        const int yo = y0 + i / WW;
        const int x  = i % WW;
        union { unsigned u; float f; } cv;
        cv.u = ((unsigned)A[(yo - ylo) * WW + x]) << 16;
        float acc = cv.f;
        #pragma unroll
        for (int d = 1; d <= RS; d++) {
            float s = 0.f;
            if (yo - d >= 0) { cv.u = ((unsigned)A[(yo - d - ylo) * WW + x]) << 16; s += cv.f; }
            if (yo + d < HH) { cv.u = ((unsigned)A[(yo + d - ylo) * WW + x]) << 16; s += cv.f; }
            acc = fmaf(w_s[d], s, acc);
        }
        B2[i] = acc;
    }
    __syncthreads();

    for (int i = tid; i < SROWS * WW; i += 256) {
        const int r = i / WW, x = i % WW;
        float acc = B2[i];
        #pragma unroll
        for (int d = 1; d <= RS; d++) {
            float s = 0.f;
            if (x - d >= 0)  s += B2[r * WW + x - d];
            if (x + d < WW)  s += B2[r * WW + x + d];
            acc = fmaf(w_s[d], s, acc);
        }
        s2T[(size_t)c * NN + (y0 + r) * WW + x] = acc;
    }
}

// Update one 256-pixel chunk (run by that chunk's 45th/last producer).
// Reads bil/s2T with agent-scope atomic loads (bypass non-coherent XCD L2).
__device__ __forceinline__ void dev_update_chunk(
    int chunk, int tid, int f, int last,
    float* bil, float* s2T, const float* uf,
    __hip_bfloat16* pTo, void* out, int* cnt,
    const float* sc, const float* sws, const float* swb)
{
    if (tid == 0)
        __hip_atomic_store(&cnt[chunk], 0, __ATOMIC_RELAXED, __HIP_MEMORY_SCOPE_AGENT);

    const int n = chunk * 256 + tid;
    float msg[CC];
    #pragma unroll
    for (int c = 0; c < CC; c++) {
        float bv = __hip_atomic_load(&bil[(size_t)c*NN + n], __ATOMIC_RELAXED,
                                     __HIP_MEMORY_SCOPE_AGENT);
        float sv = __hip_atomic_load(&s2T[(size_t)c*NN + n], __ATOMIC_RELAXED,
                                     __HIP_MEMORY_SCOPE_AGENT);
        msg[c] = fmaf(sv, sws[c], bv * swb[c]);
        bil[(size_t)c*NN + n] = 0.f;          // ready for next dispatch
    }

    float qv[CC];
    float mx = -1e30f;
    #pragma unroll
    for (int c = 0; c < CC; c++) {
        float pw = 0.f;
        #pragma unroll
        for (int cp = 0; cp < CC; cp++) pw = fmaf(msg[cp], sc[c*CC + cp], pw);
        qv[c] = uf[n*CC + c] - pw;
        mx = fmaxf(mx, qv[c]);
    }

    if (last) {
        #pragma unroll
        for (int c = 0; c < CC; c++) {
            if (f) ((float*)out)[n*CC + c] = qv[c];
            else ((__hip_bfloat16*)out)[n*CC + c] = __float2bfloat16(qv[c]);
        }
    } else {
        float s = 0.f;
        #pragma unroll
        for (int c = 0; c < CC; c++) { qv[c] = fexp(qv[c] - mx); s += qv[c]; }
        float inv = 1.f / s;
        #pragma unroll
        for (int c = 0; c < CC; c++)
            pTo[(size_t)c*NN + n] = __float2bfloat16(qv[c] * inv);
    }
}

// ======================= fused per-iteration kernel =======================
// 1116 blocks: 864 bilateral + 252 blur. Per-chunk done-counters trigger the
// inline update (non-blocking; no grid barrier, no dispatch for update).
__global__ __launch_bounds__(256, 4) void k_work(
    const __hip_bfloat16* __restrict__ pTi, __hip_bfloat16* __restrict__ pTo,
    const float* __restrict__ featx, float* __restrict__ bil,
    float* __restrict__ s2T, const float* __restrict__ uf,
    const float* __restrict__ par, const int* __restrict__ flag,
    int* __restrict__ cnt, void* __restrict__ out, int last)
{
    __shared__ __align__(16) char smem[SMEM_BYTES];
    __shared__ int sfin[3];
    const int tid = threadIdx.x;
    const int bid = blockIdx.x;

    if (bid < NBB) {
        dev_bilateral(bid, tid, pTi, featx, bil, (float*)smem);
    } else {
        dev_blur(bid - NBB, tid, pTi, s2T,
                 (unsigned short*)smem, (float*)(smem + 9216),
                 (float*)(smem + 12288));
    }
    __syncthreads();   // drains vmcnt: all stores/atomics of this block issued+complete

    if (tid == 0) {
        __threadfence();   // agent-scope release: publish s2T/bil before counting
        if (bid < NBB) {
            sfin[1] = -1; sfin[2] = -1;
            const int chunk = bid % 36;
            int old = __hip_atomic_fetch_add(&cnt[chunk], 1, __ATOMIC_ACQ_REL,
                                             __HIP_MEMORY_SCOPE_AGENT);
            sfin[0] = (old == CTARGET - 1) ? chunk : -1;
        } else {
            const int strip = (bid - NBB) / CC;
            #pragma unroll
            for (int k = 0; k < 3; k++) {
                const int chunk = 3*strip + k;
                int old = __hip_atomic_fetch_add(&cnt[chunk], 1, __ATOMIC_ACQ_REL,
                                                 __HIP_MEMORY_SCOPE_AGENT);
                sfin[k] = (old == CTARGET - 1) ? chunk : -1;
            }
        }
    }
    __syncthreads();

    if (sfin[0] >= 0 || sfin[1] >= 0 || sfin[2] >= 0) {
        __threadfence();   // acquire side
        float* sc  = (float*)smem;          // 441
        float* sws = sc + 441;              // 21
        float* swb = sws + 21;              // 21
        for (int i = tid; i < NPAR; i += 256) {
            if (i < CC)        sws[i] = par[i];
            else if (i < 2*CC) swb[i - CC] = par[i];
            else               sc[i - 2*CC] = par[i];
        }
        __syncthreads();
        const int f = *flag;
        #pragma unroll
        for (int k = 0; k < 3; k++)
            if (sfin[k] >= 0)
                dev_update_chunk(sfin[k], tid, f, last, bil, s2T, uf,
                                 pTo, out, cnt, sc, sws, swb);
    }
}

// ======================= host launcher =======================
extern "C" void kernel_launch(void* const* d_in, const int* in_sizes, int n_in,
                              void* d_out, int out_size, void* d_ws, size_t ws_size,
                              hipStream_t stream)
{
    float* ws = (float*)d_ws;
    int*   cnt   = (int*)ws;                     // [0..36) counters
    int*   flag  = (int*)ws + 40;                // dtype flag
    float* par   = ws + 64;                      // 483 floats
    float* featx = ws + 576;                     // NN*8
    __hip_bfloat16* pTA = (__hip_bfloat16*)(ws + 576 + NN*8);        // 32*NN bf16
    __hip_bfloat16* pTB = pTA + 32*NN;                               // 32*NN bf16
    float* uf  = ws + 576 + NN*8 + 32*NN;        // NELEM
    float* s2T = uf + NELEM;                     // NELEM (c-major)
    float* bil = s2T + NELEM;                    // NELEM (c-major)
    // total ~3.8 MB (ws is 256 MiB per harness poison size)

    k_prep<<<NCHUNK, 256, 0, stream>>>(d_in[0], d_in[1], d_in[2], d_in[3], d_in[4],
                                       uf, featx, par, bil, pTA, cnt, flag);

    __hip_bfloat16* bufs[2] = {pTA, pTB};
    for (int it = 0; it < 5; it++) {
        k_work<<<NJOBS, 256, 0, stream>>>(bufs[it & 1], bufs[(it + 1) & 1],
                                          featx, bil, s2T, uf, par, flag,
                                          cnt, d_out, (it == 4) ? 1 : 0);
    }
}

// Round 10
// 461.367 us; speedup vs baseline: 1.9441x; 1.1020x over previous
//
#include <hip/hip_runtime.h>
#include <hip/hip_bf16.h>

#define HH 96
#define WW 96
#define CC 21
#define NN (HH*WW)          // 9216
#define NELEM (NN*CC)       // 193536
#define RS 20               // blur radius: exp(-400/18)=2e-10 tail, negligible
#define NPAR (2*CC + CC*CC) // 483
#define L2E 1.4426950408889634f
#define MCHUNK 384
#define SKM 24              // 24*384 = 9216 m-splits
#define MSTEPS (MCHUNK/16)  // 24
#define NBB (36*SKM)        // 864 bilateral jobs
#define SROWS 8             // 8 rows per blur strip -> exactly 3 n-chunks
#define NSTRIP (HH/SROWS)   // 12
#define NBLUR (CC*NSTRIP)   // 252 blur jobs
#define NJOBS (NBB + NBLUR) // 1116
#define NCHUNK 36           // n-chunks of 256 pixels
#define CTARGET (SKM + CC)  // 45 producers per chunk
#define SMEM_BYTES 12416

typedef short bf16x8 __attribute__((ext_vector_type(8)));
typedef float f32x16 __attribute__((ext_vector_type(16)));

__device__ __forceinline__ float fexp2(float x) { return __builtin_amdgcn_exp2f(x); }
__device__ __forceinline__ float fexp(float x)  { return __builtin_amdgcn_exp2f(x * L2E); }

// pack two f32 -> two bf16 (truncation) in one v_perm_b32
__device__ __forceinline__ unsigned pk_bf16(float lo, float hi) {
    unsigned a = __builtin_bit_cast(unsigned, hi);
    unsigned b = __builtin_bit_cast(unsigned, lo);
    return __builtin_amdgcn_perm(a, b, 0x07060302u);
}

// ======================= prep (36 blocks x 256) =======================
// Every block independently sniffs dtype from ALL of u (bf16 data never has
// exp=0xFF bit patterns; fp32-as-u16 hits them ~0.4%/word), then converts its
// 256 pixels: uf, softmax->pTA (bf16 c-major), featx, params, zero bil+cnt.
__global__ __launch_bounds__(256) void k_prep(
    const void* __restrict__ u, const void* __restrict__ img,
    const void* __restrict__ wS, const void* __restrict__ wB,
    const void* __restrict__ compat,
    float* __restrict__ uf, float* __restrict__ featx, float* __restrict__ par,
    float* __restrict__ bil, __hip_bfloat16* __restrict__ pT,
    int* __restrict__ cnt, int* __restrict__ flag)
{
    __shared__ int sred[256];
    const int tid = threadIdx.x;
    const int n = blockIdx.x * 256 + tid;

    // ---- dtype sniff over whole u (193536 u16 = 24192 uint4)
    int found = 0;
    const uint4* u4 = (const uint4*)u;
    for (int i = tid; i < NELEM/8; i += 256) {
        uint4 v = u4[i];
        unsigned w;
        w = v.x; found |= ((w & 0x7F800000u) == 0x7F800000u) | ((w & 0x7F80u) == 0x7F80u);
        w = v.y; found |= ((w & 0x7F800000u) == 0x7F800000u) | ((w & 0x7F80u) == 0x7F80u);
        w = v.z; found |= ((w & 0x7F800000u) == 0x7F800000u) | ((w & 0x7F80u) == 0x7F80u);
        w = v.w; found |= ((w & 0x7F800000u) == 0x7F800000u) | ((w & 0x7F80u) == 0x7F80u);
    }
    sred[tid] = found;
    __syncthreads();
    for (int s = 128; s > 0; s >>= 1) {
        if (tid < s) sred[tid] |= sred[tid + s];
        __syncthreads();
    }
    const int f = sred[0];            // 1 = fp32 inputs, 0 = bf16

    if (blockIdx.x == 0) {
        if (tid == 0) *flag = f;
        if (tid < NCHUNK) cnt[tid] = 0;
        for (int i = tid; i < NPAR; i += 256) {
            const void* src; int j;
            if (i < CC)        { src = wS;     j = i; }
            else if (i < 2*CC) { src = wB;     j = i - CC; }
            else               { src = compat; j = i - 2*CC; }
            par[i] = f ? ((const float*)src)[j]
                       : __bfloat162float(((const __hip_bfloat16*)src)[j]);
        }
    }

    {   // featx[n]: log2-prescaled symmetric bilateral features
        float c0, c1, c2;
        if (f) { const float* p = (const float*)img;
                 c0 = p[3*n]; c1 = p[3*n+1]; c2 = p[3*n+2]; }
        else   { const __hip_bfloat16* p = (const __hip_bfloat16*)img;
                 c0 = __bfloat162float(p[3*n]); c1 = __bfloat162float(p[3*n+1]);
                 c2 = __bfloat162float(p[3*n+2]); }
        float ym = (float)(n / WW), xm = (float)(n % WW);
        const float sc = 0.15014029f;   // sqrt(2*L2E/128)
        const float cf = 9.6089787f;    // sqrt(64*L2E)
        featx[8*n + 0] = -L2E * (fmaf(ym, ym, xm*xm) * 0.0078125f
                                 + 32.f * (c0*c0 + c1*c1 + c2*c2));
        featx[8*n + 1] = sc * ym;
        featx[8*n + 2] = sc * xm;
        featx[8*n + 3] = cf * c0;
        featx[8*n + 4] = cf * c1;
        featx[8*n + 5] = cf * c2;
        featx[8*n + 6] = 0.f;
        featx[8*n + 7] = 0.f;
    }

    float v[CC];
    float mx = -1e30f;
    #pragma unroll
    for (int c = 0; c < CC; c++) {
        float uv = f ? ((const float*)u)[n*CC + c]
                     : __bfloat162float(((const __hip_bfloat16*)u)[n*CC + c]);
        uf[n*CC + c] = uv;
        v[c] = uv;
        mx = fmaxf(mx, uv);
    }
    float s = 0.f;
    #pragma unroll
    for (int c = 0; c < CC; c++) { v[c] = fexp(v[c] - mx); s += v[c]; }
    float inv = 1.f / s;
    #pragma unroll
    for (int c = 0; c < CC; c++) {
        pT[(size_t)c*NN + n] = __float2bfloat16(v[c] * inv);
        bil[(size_t)c*NN + n] = 0.f;
    }
}

// ======================= device work functions =======================

// MFMA bilateral job: bil[c][n] += sum_{m in chunk} pT[c][m] * K(n,m)
// D(32c x 32n) = A(32c x 16m) * B(16m x 32n), v_mfma_f32_32x32x16_bf16.
// pT rows 21..31 garbage -> pollute only D rows 21..31 (never stored).
__device__ __forceinline__ void dev_bilateral(
    int job, int tid, const __hip_bfloat16* pT, const float* featx,
    float* bil, float* lds_h)
{
    const int nblk = job % 36, mblk = job / 36;
    const int wv   = tid >> 6, lane = tid & 63;
    const int quad = lane >> 5, lid = lane & 31;
    const int m0c  = mblk * MCHUNK;

    {   // stage featx chunk (coalesced float4 copy)
        const float4* src = (const float4*)(featx + (size_t)m0c * 8);
        float4* dst = (float4*)lds_h;
        for (int i = tid; i < MCHUNK * 2; i += 256) dst[i] = src[i];
    }
    __syncthreads();

    const int n0 = nblk * 256 + wv * 64 + lid;    // tile0; tile1 = n0+32
    const float4 g0a = *(const float4*)(featx + (size_t)n0 * 8);
    const float4 g0b = *(const float4*)(featx + (size_t)n0 * 8 + 4);
    const float4 g1a = *(const float4*)(featx + (size_t)(n0 + 32) * 8);
    const float4 g1b = *(const float4*)(featx + (size_t)(n0 + 32) * 8 + 4);

    f32x16 acc0, acc1;
    #pragma unroll
    for (int r = 0; r < 16; r++) { acc0[r] = 0.f; acc1[r] = 0.f; }

    #pragma unroll 1
    for (int step = 0; step < MSTEPS; step++) {
        const int m0 = m0c + step * 16;
        bf16x8 afrag = *(const bf16x8*)(pT + (size_t)lid * NN + m0 + quad * 8);

        const float* h = lds_h + (step * 16 + quad * 8) * 8;
        float kb0[8], kb1[8];
        #pragma unroll
        for (int j = 0; j < 8; j++) {
            float4 ha = *(const float4*)(h + j * 8);
            float4 hb = *(const float4*)(h + j * 8 + 4);
            float s0 = g0a.x + ha.x;
            s0 = fmaf(g0a.y, ha.y, s0);
            s0 = fmaf(g0a.z, ha.z, s0);
            s0 = fmaf(g0a.w, ha.w, s0);
            s0 = fmaf(g0b.x, hb.x, s0);
            s0 = fmaf(g0b.y, hb.y, s0);
            kb0[j] = fexp2(s0);
            float s1 = g1a.x + ha.x;
            s1 = fmaf(g1a.y, ha.y, s1);
            s1 = fmaf(g1a.z, ha.z, s1);
            s1 = fmaf(g1a.w, ha.w, s1);
            s1 = fmaf(g1b.x, hb.x, s1);
            s1 = fmaf(g1b.y, hb.y, s1);
            kb1[j] = fexp2(s1);
        }
        union { bf16x8 v; unsigned d[4]; } b0u, b1u;
        #pragma unroll
        for (int d = 0; d < 4; d++) {
            b0u.d[d] = pk_bf16(kb0[2*d], kb0[2*d+1]);
            b1u.d[d] = pk_bf16(kb1[2*d], kb1[2*d+1]);
        }

        acc0 = __builtin_amdgcn_mfma_f32_32x32x16_bf16(afrag, b0u.v, acc0, 0, 0, 0);
        acc1 = __builtin_amdgcn_mfma_f32_32x32x16_bf16(afrag, b1u.v, acc1, 0, 0, 0);
    }

    // D layout: col(n) = lid, row(c) = (r&3) + 8*(r>>2) + 4*quad
    #pragma unroll
    for (int r = 0; r < 16; r++) {
        int c = (r & 3) + 8 * (r >> 2) + 4 * quad;
        if (c < CC) {
            atomicAdd(&bil[(size_t)c * NN + n0],      acc0[r]);
            atomicAdd(&bil[(size_t)c * NN + n0 + 32], acc1[r]);
        }
    }
}

// Spatial blur job: one (channel, 8-row strip). Halo kept as raw bf16.
// s2T written with agent-scope stores (bypass local L2 -> coherence point),
// so the inline finisher on another XCD reads fresh data without fences.
__device__ __forceinline__ void dev_blur(
    int job, int tid, const __hip_bfloat16* pT, float* s2T,
    unsigned short* A, float* B2, float* w_s)
{
    const int c = job % CC;
    const int strip = job / CC;
    const int y0 = strip * SROWS;
    const int ylo = (y0 - RS < 0) ? 0 : y0 - RS;
    const int yhi = (y0 + SROWS - 1 + RS > HH - 1) ? HH - 1 : y0 + SROWS - 1 + RS;
    const int nrows = yhi - ylo + 1;

    if (tid <= RS) w_s[tid] = fexp2(-(float)(tid*tid) * (L2E / 18.f));
    const unsigned short* src = (const unsigned short*)(pT + (size_t)c * NN + ylo * WW);
    for (int i = tid; i < nrows * WW; i += 256) A[i] = src[i];
    __syncthreads();

    for (int i = tid; i < SROWS * WW; i += 256) {
        const int yo = y0 + i / WW;
        const int x  = i % WW;
        union { unsigned u; float f; } cv;
        cv.u = ((unsigned)A[(yo - ylo) * WW + x]) << 16;
        float acc = cv.f;
        #pragma unroll
        for (int d = 1; d <= RS; d++) {
            float s = 0.f;
            if (yo - d >= 0) { cv.u = ((unsigned)A[(yo - d - ylo) * WW + x]) << 16; s += cv.f; }
            if (yo + d < HH) { cv.u = ((unsigned)A[(yo + d - ylo) * WW + x]) << 16; s += cv.f; }
            acc = fmaf(w_s[d], s, acc);
        }
        B2[i] = acc;
    }
    __syncthreads();

    for (int i = tid; i < SROWS * WW; i += 256) {
        const int r = i / WW, x = i % WW;
        float acc = B2[i];
        #pragma unroll
        for (int d = 1; d <= RS; d++) {
            float s = 0.f;
            if (x - d >= 0)  s += B2[r * WW + x - d];
            if (x + d < WW)  s += B2[r * WW + x + d];
            acc = fmaf(w_s[d], s, acc);
        }
        __hip_atomic_store(&s2T[(size_t)c * NN + (y0 + r) * WW + x], acc,
                           __ATOMIC_RELAXED, __HIP_MEMORY_SCOPE_AGENT);
    }
}

// Update one 256-pixel chunk (run by that chunk's 45th/last producer).
// Reads bil/s2T with agent-scope atomic loads (bypass non-coherent XCD L2).
__device__ __forceinline__ void dev_update_chunk(
    int chunk, int tid, int f, int last,
    float* bil, float* s2T, const float* uf,
    __hip_bfloat16* pTo, void* out, int* cnt,
    const float* sc, const float* sws, const float* swb)
{
    if (tid == 0)
        __hip_atomic_store(&cnt[chunk], 0, __ATOMIC_RELAXED, __HIP_MEMORY_SCOPE_AGENT);

    const int n = chunk * 256 + tid;
    float msg[CC];
    #pragma unroll
    for (int c = 0; c < CC; c++) {
        float bv = __hip_atomic_load(&bil[(size_t)c*NN + n], __ATOMIC_RELAXED,
                                     __HIP_MEMORY_SCOPE_AGENT);
        float sv = __hip_atomic_load(&s2T[(size_t)c*NN + n], __ATOMIC_RELAXED,
                                     __HIP_MEMORY_SCOPE_AGENT);
        msg[c] = fmaf(sv, sws[c], bv * swb[c]);
        bil[(size_t)c*NN + n] = 0.f;          // visible next dispatch (kernel-end flush)
    }

    float qv[CC];
    float mx = -1e30f;
    #pragma unroll
    for (int c = 0; c < CC; c++) {
        float pw = 0.f;
        #pragma unroll
        for (int cp = 0; cp < CC; cp++) pw = fmaf(msg[cp], sc[c*CC + cp], pw);
        qv[c] = uf[n*CC + c] - pw;
        mx = fmaxf(mx, qv[c]);
    }

    if (last) {
        #pragma unroll
        for (int c = 0; c < CC; c++) {
            if (f) ((float*)out)[n*CC + c] = qv[c];
            else ((__hip_bfloat16*)out)[n*CC + c] = __float2bfloat16(qv[c]);
        }
    } else {
        float s = 0.f;
        #pragma unroll
        for (int c = 0; c < CC; c++) { qv[c] = fexp(qv[c] - mx); s += qv[c]; }
        float inv = 1.f / s;
        #pragma unroll
        for (int c = 0; c < CC; c++)
            pTo[(size_t)c*NN + n] = __float2bfloat16(qv[c] * inv);
    }
}

// ======================= fused per-iteration kernel =======================
// 1116 blocks: 864 bilateral + 252 blur. Per-chunk done-counters trigger the
// inline update. NO device fences: __syncthreads() drains vmcnt(0) (all the
// block's stores/atomics complete at the coherence point) before the RELAXED
// counter bump; cross-XCD reads use agent-scope (L2-bypassing) accesses.
__global__ __launch_bounds__(256) void k_work(
    const __hip_bfloat16* __restrict__ pTi, __hip_bfloat16* __restrict__ pTo,
    const float* __restrict__ featx, float* __restrict__ bil,
    float* __restrict__ s2T, const float* __restrict__ uf,
    const float* __restrict__ par, const int* __restrict__ flag,
    int* __restrict__ cnt, void* __restrict__ out, int last)
{
    __shared__ __align__(16) char smem[SMEM_BYTES];
    __shared__ int sfin[3];
    const int tid = threadIdx.x;
    const int bid = blockIdx.x;

    if (bid < NBB) {
        dev_bilateral(bid, tid, pTi, featx, bil, (float*)smem);
    } else {
        dev_blur(bid - NBB, tid, pTi, s2T,
                 (unsigned short*)smem, (float*)(smem + 9216),
                 (float*)(smem + 12288));
    }
    __syncthreads();   // vmcnt(0): all this block's stores/atomics at coherence point

    if (tid == 0) {
        if (bid < NBB) {
            sfin[1] = -1; sfin[2] = -1;
            const int chunk = bid % 36;
            int old = __hip_atomic_fetch_add(&cnt[chunk], 1, __ATOMIC_RELAXED,
                                             __HIP_MEMORY_SCOPE_AGENT);
            sfin[0] = (old == CTARGET - 1) ? chunk : -1;
        } else {
            const int strip = (bid - NBB) / CC;
            #pragma unroll
            for (int k = 0; k < 3; k++) {
                const int chunk = 3*strip + k;
                int old = __hip_atomic_fetch_add(&cnt[chunk], 1, __ATOMIC_RELAXED,
                                                 __HIP_MEMORY_SCOPE_AGENT);
                sfin[k] = (old == CTARGET - 1) ? chunk : -1;
            }
        }
    }
    __syncthreads();

    if (sfin[0] >= 0 || sfin[1] >= 0 || sfin[2] >= 0) {
        float* sc  = (float*)smem;          // 441
        float* sws = sc + 441;              // 21
        float* swb = sws + 21;              // 21
        for (int i = tid; i < NPAR; i += 256) {
            if (i < CC)        sws[i] = par[i];
            else if (i < 2*CC) swb[i - CC] = par[i];
            else               sc[i - 2*CC] = par[i];
        }
        __syncthreads();
        const int f = *flag;
        #pragma unroll
        for (int k = 0; k < 3; k++)
            if (sfin[k] >= 0)
                dev_update_chunk(sfin[k], tid, f, last, bil, s2T, uf,
                                 pTo, out, cnt, sc, sws, swb);
    }
}

// ======================= host launcher =======================
extern "C" void kernel_launch(void* const* d_in, const int* in_sizes, int n_in,
                              void* d_out, int out_size, void* d_ws, size_t ws_size,
                              hipStream_t stream)
{
    float* ws = (float*)d_ws;
    int*   cnt   = (int*)ws;                     // [0..36) counters
    int*   flag  = (int*)ws + 40;                // dtype flag
    float* par   = ws + 64;                      // 483 floats
    float* featx = ws + 576;                     // NN*8
    __hip_bfloat16* pTA = (__hip_bfloat16*)(ws + 576 + NN*8);        // 32*NN bf16
    __hip_bfloat16* pTB = pTA + 32*NN;                               // 32*NN bf16
    float* uf  = ws + 576 + NN*8 + 32*NN;        // NELEM
    float* s2T = uf + NELEM;                     // NELEM (c-major)
    float* bil = s2T + NELEM;                    // NELEM (c-major)
    // total ~3.8 MB

    k_prep<<<NCHUNK, 256, 0, stream>>>(d_in[0], d_in[1], d_in[2], d_in[3], d_in[4],
                                       uf, featx, par, bil, pTA, cnt, flag);

    __hip_bfloat16* bufs[2] = {pTA, pTB};
    for (int it = 0; it < 5; it++) {
        k_work<<<NJOBS, 256, 0, stream>>>(bufs[it & 1], bufs[(it + 1) & 1],
                                          featx, bil, s2T, uf, par, flag,
                                          cnt, d_out, (it == 4) ? 1 : 0);
    }
}

// Round 11
// 366.053 us; speedup vs baseline: 2.4503x; 1.2604x over previous
//
#include <hip/hip_runtime.h>
#include <hip/hip_bf16.h>

#define HH 96
#define WW 96
#define CC 21
#define NN (HH*WW)          // 9216
#define NELEM (NN*CC)       // 193536
#define RS 20               // blur radius: exp(-400/18)=2e-10 tail, negligible
#define NPAR (2*CC + CC*CC) // 483
#define L2E 1.4426950408889634f
#define MCHUNK 384
#define SKM 24              // 24*384 = 9216 m-splits
#define MSTEPS (MCHUNK/16)  // 24
#define NBB (36*SKM)        // 864 bilateral jobs
#define SROWS 12            // 12 rows per blur strip
#define NSTRIP (HH/SROWS)   // 8
#define NBLUR (CC*NSTRIP)   // 168 blur jobs
#define NJOBS (NBB + NBLUR) // 1032
#define NCHUNK 36           // n-chunks of 256 pixels
#define SMEM_BYTES 14848

typedef short bf16x8 __attribute__((ext_vector_type(8)));
typedef float f32x16 __attribute__((ext_vector_type(16)));

__device__ __forceinline__ float fexp2(float x) { return __builtin_amdgcn_exp2f(x); }
__device__ __forceinline__ float fexp(float x)  { return __builtin_amdgcn_exp2f(x * L2E); }

// pack two f32 -> two bf16 (truncation) in one v_perm_b32
__device__ __forceinline__ unsigned pk_bf16(float lo, float hi) {
    unsigned a = __builtin_bit_cast(unsigned, hi);
    unsigned b = __builtin_bit_cast(unsigned, lo);
    return __builtin_amdgcn_perm(a, b, 0x07060302u);
}

// ======================= prep (36 blocks x 256) =======================
// Every block independently sniffs dtype from ALL of u (bf16 data never has
// exp=0xFF bit patterns; fp32-as-u16 hits them ~0.4%/word), then converts its
// 256 pixels: uf, softmax->pT (bf16 c-major), featx, params.
__global__ __launch_bounds__(256) void k_prep(
    const void* __restrict__ u, const void* __restrict__ img,
    const void* __restrict__ wS, const void* __restrict__ wB,
    const void* __restrict__ compat,
    float* __restrict__ uf, float* __restrict__ featx, float* __restrict__ par,
    __hip_bfloat16* __restrict__ pT, int* __restrict__ flag)
{
    __shared__ int sred[256];
    const int tid = threadIdx.x;
    const int n = blockIdx.x * 256 + tid;

    // ---- dtype sniff over whole u (193536 u16 = 24192 uint4)
    int found = 0;
    const uint4* u4 = (const uint4*)u;
    for (int i = tid; i < NELEM/8; i += 256) {
        uint4 v = u4[i];
        unsigned w;
        w = v.x; found |= ((w & 0x7F800000u) == 0x7F800000u) | ((w & 0x7F80u) == 0x7F80u);
        w = v.y; found |= ((w & 0x7F800000u) == 0x7F800000u) | ((w & 0x7F80u) == 0x7F80u);
        w = v.z; found |= ((w & 0x7F800000u) == 0x7F800000u) | ((w & 0x7F80u) == 0x7F80u);
        w = v.w; found |= ((w & 0x7F800000u) == 0x7F800000u) | ((w & 0x7F80u) == 0x7F80u);
    }
    sred[tid] = found;
    __syncthreads();
    for (int s = 128; s > 0; s >>= 1) {
        if (tid < s) sred[tid] |= sred[tid + s];
        __syncthreads();
    }
    const int f = sred[0];            // 1 = fp32 inputs, 0 = bf16

    if (blockIdx.x == 0) {
        if (tid == 0) *flag = f;
        for (int i = tid; i < NPAR; i += 256) {
            const void* src; int j;
            if (i < CC)        { src = wS;     j = i; }
            else if (i < 2*CC) { src = wB;     j = i - CC; }
            else               { src = compat; j = i - 2*CC; }
            par[i] = f ? ((const float*)src)[j]
                       : __bfloat162float(((const __hip_bfloat16*)src)[j]);
        }
    }

    {   // featx[n]: log2-prescaled symmetric bilateral features
        float c0, c1, c2;
        if (f) { const float* p = (const float*)img;
                 c0 = p[3*n]; c1 = p[3*n+1]; c2 = p[3*n+2]; }
        else   { const __hip_bfloat16* p = (const __hip_bfloat16*)img;
                 c0 = __bfloat162float(p[3*n]); c1 = __bfloat162float(p[3*n+1]);
                 c2 = __bfloat162float(p[3*n+2]); }
        float ym = (float)(n / WW), xm = (float)(n % WW);
        const float sc = 0.15014029f;   // sqrt(2*L2E/128)
        const float cf = 9.6089787f;    // sqrt(64*L2E)
        featx[8*n + 0] = -L2E * (fmaf(ym, ym, xm*xm) * 0.0078125f
                                 + 32.f * (c0*c0 + c1*c1 + c2*c2));
        featx[8*n + 1] = sc * ym;
        featx[8*n + 2] = sc * xm;
        featx[8*n + 3] = cf * c0;
        featx[8*n + 4] = cf * c1;
        featx[8*n + 5] = cf * c2;
        featx[8*n + 6] = 0.f;
        featx[8*n + 7] = 0.f;
    }

    float v[CC];
    float mx = -1e30f;
    #pragma unroll
    for (int c = 0; c < CC; c++) {
        float uv = f ? ((const float*)u)[n*CC + c]
                     : __bfloat162float(((const __hip_bfloat16*)u)[n*CC + c]);
        uf[n*CC + c] = uv;
        v[c] = uv;
        mx = fmaxf(mx, uv);
    }
    float s = 0.f;
    #pragma unroll
    for (int c = 0; c < CC; c++) { v[c] = fexp(v[c] - mx); s += v[c]; }
    float inv = 1.f / s;
    #pragma unroll
    for (int c = 0; c < CC; c++)
        pT[(size_t)c*NN + n] = __float2bfloat16(v[c] * inv);
}

// ======================= device work functions =======================

// MFMA bilateral job: partial[mblk][c][n] = sum_{m in chunk} pT[c][m] * K(n,m)
// D(32c x 32n) = A(32c x 16m) * B(16m x 32n), v_mfma_f32_32x32x16_bf16.
// pT rows 21..31 garbage -> pollute only D rows 21..31 (never stored).
// Epilogue: plain coalesced stores to a private partial slot — NO atomics.
__device__ __forceinline__ void dev_bilateral(
    int job, int tid, const __hip_bfloat16* pT, const float* featx,
    float* partial, float* lds_h)
{
    const int nblk = job % 36, mblk = job / 36;
    const int wv   = tid >> 6, lane = tid & 63;
    const int quad = lane >> 5, lid = lane & 31;
    const int m0c  = mblk * MCHUNK;

    {   // stage featx chunk (coalesced float4 copy)
        const float4* src = (const float4*)(featx + (size_t)m0c * 8);
        float4* dst = (float4*)lds_h;
        for (int i = tid; i < MCHUNK * 2; i += 256) dst[i] = src[i];
    }
    __syncthreads();

    const int n0 = nblk * 256 + wv * 64 + lid;    // tile0; tile1 = n0+32
    const float4 g0a = *(const float4*)(featx + (size_t)n0 * 8);
    const float4 g0b = *(const float4*)(featx + (size_t)n0 * 8 + 4);
    const float4 g1a = *(const float4*)(featx + (size_t)(n0 + 32) * 8);
    const float4 g1b = *(const float4*)(featx + (size_t)(n0 + 32) * 8 + 4);

    f32x16 acc0, acc1;
    #pragma unroll
    for (int r = 0; r < 16; r++) { acc0[r] = 0.f; acc1[r] = 0.f; }

    #pragma unroll 1
    for (int step = 0; step < MSTEPS; step++) {
        const int m0 = m0c + step * 16;
        bf16x8 afrag = *(const bf16x8*)(pT + (size_t)lid * NN + m0 + quad * 8);

        const float* h = lds_h + (step * 16 + quad * 8) * 8;
        float kb0[8], kb1[8];
        #pragma unroll
        for (int j = 0; j < 8; j++) {
            float4 ha = *(const float4*)(h + j * 8);
            float4 hb = *(const float4*)(h + j * 8 + 4);
            float s0 = g0a.x + ha.x;
            s0 = fmaf(g0a.y, ha.y, s0);
            s0 = fmaf(g0a.z, ha.z, s0);
            s0 = fmaf(g0a.w, ha.w, s0);
            s0 = fmaf(g0b.x, hb.x, s0);
            s0 = fmaf(g0b.y, hb.y, s0);
            kb0[j] = fexp2(s0);
            float s1 = g1a.x + ha.x;
            s1 = fmaf(g1a.y, ha.y, s1);
            s1 = fmaf(g1a.z, ha.z, s1);
            s1 = fmaf(g1a.w, ha.w, s1);
            s1 = fmaf(g1b.x, hb.x, s1);
            s1 = fmaf(g1b.y, hb.y, s1);
            kb1[j] = fexp2(s1);
        }
        union { bf16x8 v; unsigned d[4]; } b0u, b1u;
        #pragma unroll
        for (int d = 0; d < 4; d++) {
            b0u.d[d] = pk_bf16(kb0[2*d], kb0[2*d+1]);
            b1u.d[d] = pk_bf16(kb1[2*d], kb1[2*d+1]);
        }

        acc0 = __builtin_amdgcn_mfma_f32_32x32x16_bf16(afrag, b0u.v, acc0, 0, 0, 0);
        acc1 = __builtin_amdgcn_mfma_f32_32x32x16_bf16(afrag, b1u.v, acc1, 0, 0, 0);
    }

    // D layout: col(n) = lid, row(c) = (r&3) + 8*(r>>2) + 4*quad.
    // Private slot: partial[(mblk*CC + c)*NN + n] — coalesced 128B half-wave stores.
    float* dst = partial + (size_t)mblk * CC * NN;
    #pragma unroll
    for (int r = 0; r < 16; r++) {
        int c = (r & 3) + 8 * (r >> 2) + 4 * quad;
        if (c < CC) {
            dst[(size_t)c * NN + n0]      = acc0[r];
            dst[(size_t)c * NN + n0 + 32] = acc1[r];
        }
    }
}

// Spatial blur job: one (channel, 12-row strip). Halo kept as raw bf16.
__device__ __forceinline__ void dev_blur(
    int job, int tid, const __hip_bfloat16* pT, float* s2T,
    unsigned short* A, float* B2, float* w_s)
{
    const int c = job % CC;
    const int strip = job / CC;
    const int y0 = strip * SROWS;
    const int ylo = (y0 - RS < 0) ? 0 : y0 - RS;
    const int yhi = (y0 + SROWS - 1 + RS > HH - 1) ? HH - 1 : y0 + SROWS - 1 + RS;
    const int nrows = yhi - ylo + 1;

    if (tid <= RS) w_s[tid] = fexp2(-(float)(tid*tid) * (L2E / 18.f));
    const unsigned short* src = (const unsigned short*)(pT + (size_t)c * NN + ylo * WW);
    for (int i = tid; i < nrows * WW; i += 256) A[i] = src[i];
    __syncthreads();

    for (int i = tid; i < SROWS * WW; i += 256) {
        const int yo = y0 + i / WW;
        const int x  = i % WW;
        union { unsigned u; float f; } cv;
        cv.u = ((unsigned)A[(yo - ylo) * WW + x]) << 16;
        float acc = cv.f;
        #pragma unroll
        for (int d = 1; d <= RS; d++) {
            float s = 0.f;
            if (yo - d >= 0) { cv.u = ((unsigned)A[(yo - d - ylo) * WW + x]) << 16; s += cv.f; }
            if (yo + d < HH) { cv.u = ((unsigned)A[(yo + d - ylo) * WW + x]) << 16; s += cv.f; }
            acc = fmaf(w_s[d], s, acc);
        }
        B2[i] = acc;
    }
    __syncthreads();

    for (int i = tid; i < SROWS * WW; i += 256) {
        const int r = i / WW, x = i % WW;
        float acc = B2[i];
        #pragma unroll
        for (int d = 1; d <= RS; d++) {
            float s = 0.f;
            if (x - d >= 0)  s += B2[r * WW + x - d];
            if (x + d < WW)  s += B2[r * WW + x + d];
            acc = fmaf(w_s[d], s, acc);
        }
        s2T[(size_t)c * NN + (y0 + r) * WW + x] = acc;
    }
}

// ======================= per-iteration kernels =======================
// 1032 blocks: 864 bilateral + 168 blur. Pure compute, no cross-block sync.
__global__ __launch_bounds__(256) void k_work(
    const __hip_bfloat16* __restrict__ pT, const float* __restrict__ featx,
    float* __restrict__ partial, float* __restrict__ s2T)
{
    __shared__ __align__(16) char smem[SMEM_BYTES];
    const int tid = threadIdx.x;
    const int bid = blockIdx.x;

    if (bid < NBB)
        dev_bilateral(bid, tid, pT, featx, partial, (float*)smem);
    else
        dev_blur(bid - NBB, tid, pT, s2T,
                 (unsigned short*)smem, (float*)(smem + 9984),
                 (float*)(smem + 14592));
}

// Reduce 24 partials + spatial, compat transform, q-update, softmax -> pT
// (or final output on last iteration). Separate dispatch = free global barrier.
__global__ __launch_bounds__(256) void k_update(
    const float* __restrict__ partial, const float* __restrict__ s2T,
    const float* __restrict__ uf, const float* __restrict__ par,
    const int* __restrict__ flag,
    __hip_bfloat16* __restrict__ pT, void* __restrict__ out, int last)
{
    __shared__ float sc[CC*CC];
    __shared__ float sws[CC], swb[CC];
    const int tid = threadIdx.x;
    for (int i = tid; i < NPAR; i += 256) {
        if (i < CC)        sws[i] = par[i];
        else if (i < 2*CC) swb[i - CC] = par[i];
        else               sc[i - 2*CC] = par[i];
    }
    __syncthreads();

    const int n = blockIdx.x * 256 + tid;
    const int f = *flag;

    float bil[CC];
    #pragma unroll
    for (int c = 0; c < CC; c++) bil[c] = 0.f;
    #pragma unroll 1
    for (int mb = 0; mb < SKM; mb++) {
        const float* pp = partial + (size_t)mb * CC * NN + n;
        #pragma unroll
        for (int c = 0; c < CC; c++) bil[c] += pp[(size_t)c * NN];
    }

    float msg[CC];
    #pragma unroll
    for (int c = 0; c < CC; c++)
        msg[c] = fmaf(s2T[(size_t)c*NN + n], sws[c], bil[c] * swb[c]);

    float qv[CC];
    float mx = -1e30f;
    #pragma unroll
    for (int c = 0; c < CC; c++) {
        float pw = 0.f;
        #pragma unroll
        for (int cp = 0; cp < CC; cp++) pw = fmaf(msg[cp], sc[c*CC + cp], pw);
        qv[c] = uf[n*CC + c] - pw;
        mx = fmaxf(mx, qv[c]);
    }

    if (last) {
        #pragma unroll
        for (int c = 0; c < CC; c++) {
            if (f) ((float*)out)[n*CC + c] = qv[c];
            else ((__hip_bfloat16*)out)[n*CC + c] = __float2bfloat16(qv[c]);
        }
    } else {
        float s = 0.f;
        #pragma unroll
        for (int c = 0; c < CC; c++) { qv[c] = fexp(qv[c] - mx); s += qv[c]; }
        float inv = 1.f / s;
        #pragma unroll
        for (int c = 0; c < CC; c++)
            pT[(size_t)c*NN + n] = __float2bfloat16(qv[c] * inv);
    }
}

// ======================= host launcher =======================
extern "C" void kernel_launch(void* const* d_in, const int* in_sizes, int n_in,
                              void* d_out, int out_size, void* d_ws, size_t ws_size,
                              hipStream_t stream)
{
    float* ws = (float*)d_ws;
    int*   flag  = (int*)ws + 40;                // dtype flag
    float* par   = ws + 64;                      // 483 floats
    float* featx = ws + 576;                     // NN*8
    __hip_bfloat16* pT = (__hip_bfloat16*)(ws + 576 + NN*8);   // 32*NN bf16
    float* uf      = ws + 576 + NN*8 + 16*NN;    // NELEM
    float* s2T     = uf + NELEM;                 // NELEM (c-major)
    float* partial = s2T + NELEM;                // SKM*CC*NN = 18.6 MB
    // total ~ 21 MB (ws is 256 MiB)

    k_prep<<<NCHUNK, 256, 0, stream>>>(d_in[0], d_in[1], d_in[2], d_in[3], d_in[4],
                                       uf, featx, par, pT, flag);

    for (int it = 0; it < 5; it++) {
        k_work<<<NJOBS, 256, 0, stream>>>(pT, featx, partial, s2T);
        k_update<<<NCHUNK, 256, 0, stream>>>(partial, s2T, uf, par, flag,
                                             pT, d_out, (it == 4) ? 1 : 0);
    }
}